// Round 8
// baseline (204.524 us; speedup 1.0000x reference)
//
#include <hip/hip_runtime.h>

#define NB 256
#define NT 1024
#define NL 64

typedef __fp16 h2v __attribute__((ext_vector_type(2)));

__device__ __forceinline__ float rfl_f(float v) {
  return __builtin_bit_cast(float, __builtin_amdgcn_readfirstlane(__builtin_bit_cast(int, v)));
}

// partner = value from lane^1, via DPP quad_perm [1,0,3,2] (VALU, no LDS pipe)
__device__ __forceinline__ float dpp_xor1(float v) {
  int i = __builtin_bit_cast(int, v);
  int r = __builtin_amdgcn_update_dpp(i, i, 0xB1, 0xF, 0xF, false);
  return __builtin_bit_cast(float, r);
}

#define DOT4(P, B)                                                            \
  s0 = __builtin_amdgcn_fdot2(__builtin_bit_cast(h2v, (P).x), Rh[(B) + 0], s0, false); \
  s1 = __builtin_amdgcn_fdot2(__builtin_bit_cast(h2v, (P).y), Rh[(B) + 1], s1, false); \
  s2 = __builtin_amdgcn_fdot2(__builtin_bit_cast(h2v, (P).z), Rh[(B) + 2], s2, false); \
  s3 = __builtin_amdgcn_fdot2(__builtin_bit_cast(h2v, (P).w), Rh[(B) + 3], s3, false);

// One CRF step — BIT-IDENTICAL to the round-0 verified kernel (436 cy/step,
// absmax 0). All gather restructures (r1-r4) and F/B pairing (r6) measured
// slower wall-clock. Do not touch.
#define CRF_STEP(EF)                                                          \
  do {                                                                        \
    float wn = dpp_xor1(w);                                                   \
    h2v pk = __builtin_amdgcn_cvt_pkrtz(w, wn);                               \
    lb[wslot] = __builtin_bit_cast(int, pk);                                  \
    int4 P0 = lbv[0], P1 = lbv[1], P2 = lbv[2], P3 = lbv[3];                  \
    int4 P4 = lbv[4], P5 = lbv[5], P6 = lbv[6], P7 = lbv[7];                  \
    int e5 = (P0.x >> 10) & 0x1f;                                             \
    float K = __builtin_bit_cast(float, (130 - e5) << 23);                    \
    float KE = K * (EF);                                                      \
    e2 += e5 - 3;                                                             \
    float s0 = 0.f, s1 = 0.f, s2 = 0.f, s3 = 0.f;                             \
    DOT4(P0, 0); DOT4(P1, 4); DOT4(P2, 8); DOT4(P3, 12);                      \
    DOT4(P4, 16); DOT4(P5, 20); DOT4(P6, 24); DOT4(P7, 28);                   \
    w = ((s0 + s1) + (s2 + s3)) * KE;                                         \
  } while (0)

#define AQ __ATOMIC_ACQUIRE
#define RL __ATOMIC_RELEASE
#define SCOPE __HIP_MEMORY_SCOPE_AGENT

// 256 blocks x 192 threads. Block b = batch b: wave 0 runs the fwd chain,
// wave 1 the bwd chain (each bit-identical r0 chains, concurrent on separate
// SIMDs), wave 2 the gold path. Combine is INTRA-BLOCK (__syncthreads + LDS)
// — the r5/r7 lesson: cross-block agent-scope spin-waits inside the chain
// kernel cost ~35us (fb 130 vs 93); no-spin versions (r0, r6) match chain
// arithmetic exactly. Cross-block sync only in the r6-proven-free form:
// per-block flag + block-0 poll AFTER all work. 256x3 waves = 768 = r0's
// occupancy exactly (1 block/CU).
__global__ __launch_bounds__(192) void fb_kernel(const float* __restrict__ scores,
                                                 const int* __restrict__ targets,
                                                 const float* __restrict__ start,
                                                 const float* __restrict__ Tm,
                                                 const float* __restrict__ endv,
                                                 float* __restrict__ wsL,
                                                 int* __restrict__ flagL,
                                                 float* __restrict__ out) {
  const int lane = threadIdx.x & 63;
  const int wv = threadIdx.x >> 6;  // 0 = fwd, 1 = bwd, 2 = gold
  const int b = blockIdx.x;
  const float* sc = scores + (size_t)b * NT * NL;
  const float LN2 = 0.69314718055994530942f;

  __shared__ int4 lbv_s[2][16];  // per-chain-wave 64-word broadcast regions
  __shared__ float shA[NL];      // alpha_512 (log-space, per state)
  __shared__ float shB[NL];      // beta_512
  __shared__ float shG;          // gold score

  if (wv == 2) {  // ---- gold path (r0 code) ----
    const int* tg = targets + b * NT;
    float acc = 0.f;
#pragma unroll
    for (int k = 0; k < 16; k++) {
      int t = lane + 64 * k;
      int c = tg[t];
      acc += sc[t * NL + c];
      if (t > 0) acc += Tm[c * NL + tg[t - 1]];  // T_mat[cur, prev]
    }
#pragma unroll
    for (int off = 32; off > 0; off >>= 1) acc += __shfl_xor(acc, off, 64);
    if (lane == 0) shG = acc + start[tg[0]] + endv[tg[NT - 1]];
  } else {  // ---- chain waves (r0 code, one chain per wave) ----
    int* lb = (int*)lbv_s[wv];
    const int4* lbv = lbv_s[wv];
    const int wslot = (lane & 1) * 32 + (lane >> 1);  // 2 lanes/bank -> free

    const bool bwd = wv == 1;
    // f16x2 transition table: fwd Rh[k] = (exp(T[lane][2k]), exp(T[lane][2k+1]))
    //                         bwd Rh[k] = (exp(T[2k][lane]), exp(T[2k+1][lane]))
    const float* Tb = bwd ? (Tm + lane) : (Tm + lane * NL);
    const int str = bwd ? NL : 1;
    h2v Rh[32];
#pragma unroll
    for (int k = 0; k < 32; k++)
      Rh[k] = __builtin_amdgcn_cvt_pkrtz(__expf(Tb[(2 * k) * str]),
                                         __expf(Tb[(2 * k + 1) * str]));

    if (!bwd) {
      float a0 = start[lane] + sc[lane];  // alpha_0
      float m0 = rfl_f(a0);
      float w = __expf(a0 - m0) * 16.f;   // keep w_0 in f16-normal range
      int e2 = -4;

      float buf[4];
#pragma unroll
      for (int k = 0; k < 4; k++) buf[k] = sc[(1 + k) * NL + lane];

      for (int i = 0; i < 128; i++) {  // 512 steps: t = 1..512
        float nb4[4];
        int tb = 5 + 4 * i;  // prefetch (max t=516 < 1024)
#pragma unroll
        for (int k = 0; k < 4; k++) nb4[k] = sc[(tb + k) * NL + lane];
        float Ev[4];
#pragma unroll
        for (int k = 0; k < 4; k++) Ev[k] = __expf(buf[k]);  // off critical chain
        CRF_STEP(Ev[0]);
        CRF_STEP(Ev[1]);
        CRF_STEP(Ev[2]);
        CRF_STEP(Ev[3]);
#pragma unroll
        for (int k = 0; k < 4; k++) buf[k] = nb4[k];
      }
      shA[lane] = m0 + (float)e2 * LN2 + __logf(w);  // alpha_512
    } else {
      float a0 = endv[lane] + sc[(NT - 1) * NL + lane];
      float m0 = rfl_f(a0);
      float w = __expf(a0 - m0) * 16.f;
      int e2 = -4;

      float buf[4];
#pragma unroll
      for (int k = 0; k < 4; k++) buf[k] = sc[(1022 - k) * NL + lane];

      for (int i = 0; i < 127; i++) {  // 508 steps: te = 1022..515
        float nb4[4];
        int tb = 1018 - 4 * i;  // prefetch (min 511 >= 0)
#pragma unroll
        for (int k = 0; k < 4; k++) nb4[k] = sc[(tb - k) * NL + lane];
        float Ev[4];
#pragma unroll
        for (int k = 0; k < 4; k++) Ev[k] = __expf(buf[k]);
        CRF_STEP(Ev[0]);
        CRF_STEP(Ev[1]);
        CRF_STEP(Ev[2]);
        CRF_STEP(Ev[3]);
#pragma unroll
        for (int k = 0; k < 4; k++) buf[k] = nb4[k];
      }
      CRF_STEP(__expf(sc[514 * NL + lane]));
      CRF_STEP(__expf(sc[513 * NL + lane]));
      CRF_STEP(1.0f);  // final matvec-only step -> beta_512
      shB[lane] = m0 + (float)e2 * LN2 + __logf(w);
    }
  }

  __syncthreads();  // intra-block barrier: ~100 cy, no agent-scope traffic

  if (wv == 0) {  // ---- combine: lse(alpha+beta) - gold, all in-block ----
    float v = shA[lane] + shB[lane];
    float m = v;
#pragma unroll
    for (int off = 32; off > 0; off >>= 1) m = fmaxf(m, __shfl_xor(m, off, 64));
    float s = __expf(v - m);
#pragma unroll
    for (int off = 32; off > 0; off >>= 1) s += __shfl_xor(s, off, 64);
    float loss = (m + __logf(s)) - shG;

    if (lane == 0) {
      wsL[b] = loss;
      __threadfence();
      __hip_atomic_store(&flagL[b], 1, RL, SCOPE);
    }

    if (b == 0) {  // ---- finisher (r6-verified, zero marginal cost) ----
      for (;;) {
        int f0 = __hip_atomic_load(&flagL[lane], AQ, SCOPE);
        int f1 = __hip_atomic_load(&flagL[lane + 64], AQ, SCOPE);
        int f2 = __hip_atomic_load(&flagL[lane + 128], AQ, SCOPE);
        int f3 = __hip_atomic_load(&flagL[lane + 192], AQ, SCOPE);
        if (__all((f0 & f1 & f2 & f3) != 0)) break;
        __builtin_amdgcn_s_sleep(8);
      }
      float t0 = __builtin_bit_cast(float, __hip_atomic_load((int*)&wsL[lane], AQ, SCOPE));
      float t1 = __builtin_bit_cast(float, __hip_atomic_load((int*)&wsL[lane + 64], AQ, SCOPE));
      float t2 = __builtin_bit_cast(float, __hip_atomic_load((int*)&wsL[lane + 128], AQ, SCOPE));
      float t3 = __builtin_bit_cast(float, __hip_atomic_load((int*)&wsL[lane + 192], AQ, SCOPE));
      float tot = (t0 + t1) + (t2 + t3);
#pragma unroll
      for (int off = 32; off > 0; off >>= 1) tot += __shfl_xor(tot, off, 64);
      if (lane == 0) out[0] = tot * (1.0f / NB);
    }
  }
}

extern "C" void kernel_launch(void* const* d_in, const int* in_sizes, int n_in,
                              void* d_out, int out_size, void* d_ws, size_t ws_size,
                              hipStream_t stream) {
  const float* scores = (const float*)d_in[0];
  const int* targets = (const int*)d_in[1];
  const float* start = (const float*)d_in[2];
  const float* Tm = (const float*)d_in[3];
  const float* endv = (const float*)d_in[4];
  float* out = (float*)d_out;

  int* flagL = (int*)d_ws;             // [NB] per-batch done flags
  float* wsL = (float*)(flagL + NB);   // [NB] per-batch losses

  hipMemsetAsync(flagL, 0, NB * sizeof(int), stream);
  fb_kernel<<<NB, 192, 0, stream>>>(scores, targets, start, Tm, endv, wsL, flagL, out);
}